// Round 1
// 341.797 us; speedup vs baseline: 1.0143x; 1.0143x over previous
//
#include <hip/hip_runtime.h>
#include <hip/hip_fp16.h>

// Problem: B=8192, L=64, M=64, LOCAL_DIM=4, eps shape (4, 64, 64, 65, 65) f32.
// out[b] = sum_m prod_l eps[idx[b,l], m, l, nup[b,l], ndn[b,l]]
// nup/ndn = exclusive cumsum of bit0/bit1 of idx along l.
//
// eps element strides: d:17305600, m:270400, l:4225, u:65, n:1
// Compact transposed table (reachable u<=l, n<=l states), fp16:
//   tab[(P_l + u*(l+1) + n)*256 + d*64 + m],  P_l = l(l+1)(2l+1)/6
// fp16 accuracy: eps ~[0.7,1.3]; product-of-64 rel err ~2.3e-3; absmax 0.5
// observed vs 1.56 threshold.
//
// R4: only transpose states actually VISITED by this batch (per-l
// [umin,umax]x[nmin,nmax] pre-pass). ~3.5x less transpose traffic.
//
// R5 (this round): seggps_main was issue-bound, not BW-bound (67 MB of
// L2/L3-resident gathers; 524k wave-loads + 2 shuffles + ~20 VALU per
// 2 batches per site). New main: 4 batches/wave, 16 lanes each, ushort4
// (8B) gathers -> 4x fewer VMEM instrs, indices of 4 batches packed 2b
// each into one int -> 1 shuffle/site/wave, 1 address/lane/site.

#define TAB_HALF_BYTES ((size_t)89440 * 256 * 2)

__global__ __launch_bounds__(256) void seggps_init(int* __restrict__ ranges) {
  int t = threadIdx.x;
  if (t < 64) {
    ranges[t] = 64;        // umin
    ranges[64 + t] = -1;   // umax
    ranges[128 + t] = 64;  // nmin
    ranges[192 + t] = -1;  // nmax
  }
}

// grid = 128 blocks x 256 thr; block handles 64 batches. Wave prefix-scan
// gives each batch's (u,n) at every l; LDS min/max then 256 global atomics.
__global__ __launch_bounds__(256) void seggps_ranges(
    const int* __restrict__ indices, int* __restrict__ ranges) {
  __shared__ int s_umin[64], s_umax[64], s_nmin[64], s_nmax[64];
  int t = threadIdx.x;
  if (t < 64) { s_umin[t] = 64; s_umax[t] = -1; s_nmin[t] = 64; s_nmax[t] = -1; }
  __syncthreads();
  int wave = t >> 6, lane = t & 63;    // lane = l
  for (int i = 0; i < 16; ++i) {
    int b = blockIdx.x * 64 + wave * 16 + i;
    int v = indices[b * 64 + lane];
    int up = v & 1, dn = (v >> 1) & 1;
#pragma unroll
    for (int s = 1; s < 64; s <<= 1) { // inclusive scan across lanes
      int au = __shfl_up(up, s, 64);
      int ad = __shfl_up(dn, s, 64);
      if (lane >= s) { up += au; dn += ad; }
    }
    int eu = up - (v & 1);             // exclusive
    int ed = dn - ((v >> 1) & 1);
    atomicMin(&s_umin[lane], eu); atomicMax(&s_umax[lane], eu);
    atomicMin(&s_nmin[lane], ed); atomicMax(&s_nmax[lane], ed);
  }
  __syncthreads();
  if (t < 64) {
    atomicMin(&ranges[t], s_umin[t]);
    atomicMax(&ranges[64 + t], s_umax[t]);
    atomicMin(&ranges[128 + t], s_nmin[t]);
    atomicMax(&ranges[192 + t], s_nmax[t]);
  }
}

__global__ __launch_bounds__(256) void seggps_transpose(
    const float* __restrict__ eps, __half* __restrict__ tab,
    const int* __restrict__ ranges) {
  int bid = blockIdx.x;                 // grid = 4 * 2080 (triangular)
  int d = bid / 2080;
  int t = bid % 2080;
  int l = (int)((sqrtf(8.0f * (float)t + 1.0f) - 1.0f) * 0.5f);
  while ((l + 1) * (l + 2) / 2 <= t) ++l;   // fix fp rounding
  while (l * (l + 1) / 2 > t) --l;
  int u = t - l * (l + 1) / 2;

  int umin = ranges[l], umax = ranges[64 + l];
  if (u < umin || u > umax) return;     // no batch visits this u at site l
  int nmin = ranges[128 + l], nmax = ranges[192 + l];  // nmax <= l always

  int lane = threadIdx.x & 63;          // n on load, m on store
  int wave = threadIdx.x >> 6;          // 4 waves

  __shared__ float tile[64][65];        // [m][n]

  // load: coalesced along n (stride 1 in eps); nontemporal (no reuse)
  const float* src = eps + ((size_t)(d * 64) * 64 + l) * 4225 + u * 65;
  if (lane >= nmin && lane <= nmax) {
#pragma unroll 4
    for (int m = wave; m < 64; m += 4) {
      tile[m][lane] = __builtin_nontemporal_load(&src[(size_t)m * 270400 + lane]);
    }
  }
  __syncthreads();

  // store: coalesced along m (128B contiguous per wave)
  int Pl = l * (l + 1) * (2 * l + 1) / 6;
  __half* dst = tab + (size_t)(Pl + u * (l + 1)) * 256 + d * 64 + lane;
  for (int n = nmin + wave; n <= nmax; n += 4) {
    dst[n * 256] = __float2half(tile[lane][n]);
  }
}

// R5 main: 4 batches per wave. Lane layout: g = lane>>4 selects the batch,
// Lm = lane&15 selects an m-quad (m = 4*Lm .. 4*Lm+3, ushort4 = 8B load,
// 16 lanes x 8B = one 128B line per batch-group per site). Indices of the
// 4 batches are packed 2 bits each into one int -> one __shfl per site.
// Four independent f32 product chains per lane (one per m), summed at the
// end and reduced across the 16-lane group.
__global__ __launch_bounds__(256, 4) void seggps_main(
    const int* __restrict__ indices, const __half* __restrict__ tab,
    float* __restrict__ out) {
  int wave = threadIdx.x >> 6;
  int lane = threadIdx.x & 63;
  int g = lane >> 4;                    // batch subgroup 0..3
  int Lm = lane & 15;                   // m-quad index
  int b0 = (blockIdx.x * 4 + wave) * 4; // this wave handles b0 .. b0+3

  // pack 4 batches' site-lane index values, 2 bits each
  int ipk = indices[(b0 + 0) * 64 + lane]
          | (indices[(b0 + 1) * 64 + lane] << 2)
          | (indices[(b0 + 2) * 64 + lane] << 4)
          | (indices[(b0 + 3) * 64 + lane] << 6);

  float p0 = 1.f, p1 = 1.f, p2 = 1.f, p3 = 1.f;
  int up = 0, dn = 0;                   // this lane's batch's counters
  int Pl = 0;                           // l(l+1)(2l+1)/6, built incrementally
  int mbase = Lm * 4;
#pragma unroll 16
  for (int l = 0; l < 64; ++l) {
    int s = __shfl(ipk, l, 64);
    int v = (s >> (2 * g)) & 3;
    int o = (Pl + up * (l + 1) + dn) * 256 + v * 64 + mbase;
    ushort4 q = *reinterpret_cast<const ushort4*>(tab + o);  // 8B, aligned
    p0 *= __half2float(__ushort_as_half(q.x));
    p1 *= __half2float(__ushort_as_half(q.y));
    p2 *= __half2float(__ushort_as_half(q.z));
    p3 *= __half2float(__ushort_as_half(q.w));
    up += v & 1;
    dn += (v >> 1) & 1;
    Pl += (l + 1) * (l + 1);
  }
  // p0..p3 are products for four DIFFERENT m -> sum, then reduce over the
  // 16-lane group (width=16 keeps the shuffle inside the group).
  float r = (p0 + p1) + (p2 + p3);
#pragma unroll
  for (int s = 8; s; s >>= 1) r += __shfl_down(r, s, 16);
  if (Lm == 0) out[b0 + g] = r;
}

// Fallback if workspace is too small: gather straight from eps.
__global__ __launch_bounds__(256) void seggps_direct(
    const int* __restrict__ indices, const float* __restrict__ eps,
    float* __restrict__ out) {
  int wave = threadIdx.x >> 6;
  int lane = threadIdx.x & 63;          // lane = m
  int b = blockIdx.x * 4 + wave;

  int myidx = indices[b * 64 + lane];

  float p0 = 1.f, p1 = 1.f, p2 = 1.f, p3 = 1.f;
  int up = 0, dn = 0;
#pragma unroll 8
  for (int l = 0; l < 64; ++l) {
    int v = __shfl(myidx, l, 64);
    size_t off = ((size_t)((v * 64 + lane) * 64 + l)) * 4225 + up * 65 + dn;
    float e = eps[off];
    if ((l & 3) == 0)      p0 *= e;
    else if ((l & 3) == 1) p1 *= e;
    else if ((l & 3) == 2) p2 *= e;
    else                   p3 *= e;
    up += v & 1;
    dn += (v >> 1) & 1;
  }
  float p = (p0 * p1) * (p2 * p3);
#pragma unroll
  for (int s = 32; s; s >>= 1) p += __shfl_down(p, s, 64);
  if (lane == 0) out[b] = p;
}

extern "C" void kernel_launch(void* const* d_in, const int* in_sizes, int n_in,
                              void* d_out, int out_size, void* d_ws, size_t ws_size,
                              hipStream_t stream) {
  const int* indices = (const int*)d_in[0];   // (8192, 64) int
  const float* eps   = (const float*)d_in[1]; // (4, 64, 64, 65, 65) f32
  float* out = (float*)d_out;                 // (8192,) f32

  if (ws_size >= TAB_HALF_BYTES + 1024) {
    __half* tab = (__half*)d_ws;
    int* ranges = (int*)((char*)d_ws + TAB_HALF_BYTES);  // 256 ints
    hipLaunchKernelGGL(seggps_init, dim3(1), dim3(256), 0, stream, ranges);
    hipLaunchKernelGGL(seggps_ranges, dim3(128), dim3(256), 0, stream,
                       indices, ranges);
    hipLaunchKernelGGL(seggps_transpose, dim3(4 * 2080), dim3(256), 0, stream,
                       eps, tab, ranges);
    hipLaunchKernelGGL(seggps_main, dim3(8192 / 16), dim3(256), 0, stream,
                       indices, tab, out);
  } else {
    hipLaunchKernelGGL(seggps_direct, dim3(8192 / 4), dim3(256), 0, stream,
                       indices, eps, out);
  }
}